// Round 17
// baseline (169.868 us; speedup 1.0000x reference)
//
#include <hip/hip_runtime.h>
#include <hip/hip_bf16.h>
#include <cmath>

typedef __attribute__((ext_vector_type(8))) short bf16x8;
typedef __attribute__((ext_vector_type(4))) short bf16x4;
typedef __attribute__((ext_vector_type(4))) float f32x4;

constexpr int Tq  = 2048;
constexpr int Dm  = 1024;
constexpr int NHC = 16;
constexpr int HDC = 64;
constexpr int TDC = 256;
constexpr int KSEL = 26;   // ceil(204/8): 26th-largest distinct value
constexpr int CH  = 8;     // j-tiles (of 64) per split-j chunk

__device__ inline ushort f2bf(float x) {
  union { float f; unsigned u; } v; v.f = x;
  return (ushort)((v.u + 0x7FFF + ((v.u >> 16) & 1)) >> 16);
}
__device__ inline float bf2f(ushort b) {
  union { unsigned u; float f; } v; v.u = ((unsigned)b) << 16;
  return v.f;
}
// async global->LDS, 16B per lane; LDS dest = wave-uniform base + lane*16
__device__ inline void gload16(const ushort* g, ushort* l) {
  __builtin_amdgcn_global_load_lds(
      (const __attribute__((address_space(1))) unsigned int*)g,
      (__attribute__((address_space(3))) unsigned int*)l, 16, 0, 0);
}

// ---------------------------------------------------------------------------
// Fused split-cast of x + 4 weight matrices, flat 1D grid (6144 blocks).
// ---------------------------------------------------------------------------
__global__ __launch_bounds__(256) void cast_split_all(
    const float* __restrict__ x,  const float* __restrict__ wq,
    const float* __restrict__ wk, const float* __restrict__ wv,
    const float* __restrict__ wo,
    ushort* __restrict__ xh,  ushort* __restrict__ xl,
    ushort* __restrict__ wqh, ushort* __restrict__ wql,
    ushort* __restrict__ wkh, ushort* __restrict__ wkl,
    ushort* __restrict__ wvh, ushort* __restrict__ wvl,
    ushort* __restrict__ woh, ushort* __restrict__ wol) {
  int bid = blockIdx.x;
  const float* src; ushort *hi, *lo; int blk;
  if (bid < 2048)      { src = x;  hi = xh;  lo = xl;  blk = bid; }
  else {
    int z = (bid - 2048) >> 10;
    blk = (bid - 2048) & 1023;
    if (z == 0)      { src = wq; hi = wqh; lo = wql; }
    else if (z == 1) { src = wk; hi = wkh; lo = wkl; }
    else if (z == 2) { src = wv; hi = wvh; lo = wvl; }
    else             { src = wo; hi = woh; lo = wol; }
  }
  int base = (blk * 256 + threadIdx.x) * 4;
  float4 v = *(const float4*)&src[base];
  ushort h0 = f2bf(v.x), h1 = f2bf(v.y), h2 = f2bf(v.z), h3 = f2bf(v.w);
  *(ushort4*)&hi[base] = make_ushort4(h0, h1, h2, h3);
  *(ushort4*)&lo[base] = make_ushort4(
      f2bf(v.x - bf2f(h0)), f2bf(v.y - bf2f(h1)),
      f2bf(v.z - bf2f(h2)), f2bf(v.w - bf2f(h3)));
}

// ---------------------------------------------------------------------------
// FUSED GEMM launch, 1D grid of EXACTLY 512 blocks (2/CU), 64KB LDS:
//   bid <  128 : exact fp32 Qd/Kd GEMM (BK=16 dbuf body, bit-identical);
//                blocks 0..63 additionally run xpart AFTER the GEMM.
//   bid >= 128 : 128x128 split-bf16 MFMA Q/K/V GEMM, XCD-swizzled,
//                setprio(1) around the MFMA cluster (T5: wins issue
//                arbitration vs co-resident fp32 VALU blocks).
// ---------------------------------------------------------------------------
__global__ __launch_bounds__(256, 2) void fused_gemms(
    const float* __restrict__ x, const float* __restrict__ wq,
    const float* __restrict__ wk, float* __restrict__ Qd,
    float* __restrict__ Kd, float* __restrict__ xp,
    const ushort* __restrict__ xh_, const ushort* __restrict__ xl_,
    const ushort* __restrict__ wqh_, const ushort* __restrict__ wql_,
    const ushort* __restrict__ wkh_, const ushort* __restrict__ wkl_,
    const ushort* __restrict__ wvh_, const ushort* __restrict__ wvl_,
    ushort* __restrict__ Qh, ushort* __restrict__ Ql,
    ushort* __restrict__ Kh, ushort* __restrict__ Kl,
    ushort* __restrict__ Vth) {
  __shared__ __align__(16) char smem[65536];
  int bid = blockIdx.x;
  int tid = threadIdx.x;
  if (bid < 128) {
    // ---- exact fp32 Qd/Kd (mask path), 64x64 tile, BK=16 double-buffered ----
    int mat = bid >> 6;
    int rem = bid & 63;
    int n0 = (rem & 15) * 64, m0 = (rem >> 4) * 64;
    const float* B = mat ? wk : wq;
    float* C = mat ? Kd : Qd;
    typedef float lds16x68[16][68];
    lds16x68* As = (lds16x68*)(smem);                       // [2][16][68]
    lds16x68* Bs = (lds16x68*)(smem + 2 * 16 * 68 * 4);     // [2][16][68]
    int tx = tid & 15, ty = tid >> 4;
    int srow = tid >> 2, sc4 = tid & 3;
    const float* Arow = &x[(size_t)((m0 + srow) * 8) * 1024 + sc4 * 4];
    const float* Brow = &B[(size_t)(n0 + srow) * 1024 + sc4 * 4];
    float acc[4][4] = {};
    {
      float4 av = *(const float4*)&Arow[0];
      float4 bv = *(const float4*)&Brow[0];
      As[0][sc4 * 4 + 0][srow] = av.x; As[0][sc4 * 4 + 1][srow] = av.y;
      As[0][sc4 * 4 + 2][srow] = av.z; As[0][sc4 * 4 + 3][srow] = av.w;
      Bs[0][sc4 * 4 + 0][srow] = bv.x; Bs[0][sc4 * 4 + 1][srow] = bv.y;
      Bs[0][sc4 * 4 + 2][srow] = bv.z; Bs[0][sc4 * 4 + 3][srow] = bv.w;
    }
    __syncthreads();
    for (int iter = 0; iter < 64; ++iter) {
      int cbuf = iter & 1, nbuf = cbuf ^ 1;
      bool hn = (iter + 1 < 64);
      float4 av, bv;
      if (hn) {
        int k0 = (iter + 1) * 16;
        av = *(const float4*)&Arow[k0];
        bv = *(const float4*)&Brow[k0];
      }
#pragma unroll
      for (int k = 0; k < 16; ++k) {
        float a[4], b[4];
#pragma unroll
        for (int i = 0; i < 4; ++i) {
          a[i] = As[cbuf][k][ty * 4 + i];
          b[i] = Bs[cbuf][k][tx * 4 + i];
        }
#pragma unroll
        for (int i = 0; i < 4; ++i)
#pragma unroll
          for (int j = 0; j < 4; ++j) acc[i][j] += a[i] * b[j];
      }
      if (hn) {
        As[nbuf][sc4 * 4 + 0][srow] = av.x; As[nbuf][sc4 * 4 + 1][srow] = av.y;
        As[nbuf][sc4 * 4 + 2][srow] = av.z; As[nbuf][sc4 * 4 + 3][srow] = av.w;
        Bs[nbuf][sc4 * 4 + 0][srow] = bv.x; Bs[nbuf][sc4 * 4 + 1][srow] = bv.y;
        Bs[nbuf][sc4 * 4 + 2][srow] = bv.z; Bs[nbuf][sc4 * 4 + 3][srow] = bv.w;
      }
      __syncthreads();
    }
#pragma unroll
    for (int i = 0; i < 4; ++i)
#pragma unroll
      for (int j = 0; j < 4; ++j)
        C[(size_t)(m0 + ty * 4 + i) * 1024 + n0 + tx * 4 + j] = acc[i][j];
    // ---- blocks 0..63 append xpart (verbatim per-thread code) ----
    if (bid < 64) {
      int b = bid;
      float4 s = {0.f, 0.f, 0.f, 0.f};
      for (int r = 0; r < 32; ++r) {
        float4 v = *(const float4*)&x[(size_t)(b * 32 + r) * Dm + tid * 4];
        s.x += v.x; s.y += v.y; s.z += v.z; s.w += v.w;
      }
      *(float4*)&xp[b * Dm + tid * 4] = s;
    }
    return;
  }
  // ---- 128x128 split-bf16 MFMA Q/K/V, XCD-swizzled (bit-identical body) ----
  int q_ = bid - 128;                 // 0..383, 384 % 8 == 0
  int xcd = q_ & 7, j_ = q_ >> 3;     // j_ 0..47
  int panel = xcd * 3 + (j_ >> 4);    // 0..23: (z, n_t) panel
  int m_t = j_ & 15;
  int z = panel >> 3, n_t = panel & 7;
  int n0 = n_t * 128, m0 = m_t * 128;
  const ushort* Bhp = (z == 0) ? wqh_ : ((z == 1) ? wkh_ : wvh_);
  const ushort* Blp = (z == 0) ? wql_ : ((z == 1) ? wkl_ : wvl_);
  ushort (*AhS)[64] = (ushort(*)[64])(smem);
  ushort (*AlS)[64] = (ushort(*)[64])(smem + 16384);
  ushort (*BhS)[64] = (ushort(*)[64])(smem + 32768);
  ushort (*BlS)[64] = (ushort(*)[64])(smem + 49152);
  int w = tid >> 6, l = tid & 63, l15 = l & 15, lg = l >> 4;
  int qr = w >> 1, qc = w & 1;
  int lrow = l >> 3, lc8 = l & 7;
  f32x4 acc[4][4] = {};
  for (int k0 = 0; k0 < Dm; k0 += 64) {
    __syncthreads();
#pragma unroll
    for (int s = 0; s < 4; ++s) {
      int row = 32 * w + s * 8 + lrow;
      int scol = (lc8 ^ (row & 7)) * 8;
      size_t ao = (size_t)(m0 + row) * Dm + k0 + scol;
      size_t bo = (size_t)(n0 + row) * Dm + k0 + scol;
      gload16(&xh_[ao], &AhS[32 * w + s * 8][0]);
      gload16(&xl_[ao], &AlS[32 * w + s * 8][0]);
      gload16(&Bhp[bo], &BhS[32 * w + s * 8][0]);
      gload16(&Blp[bo], &BlS[32 * w + s * 8][0]);
    }
    __syncthreads();
#pragma unroll
    for (int kst = 0; kst < 2; ++kst) {
      bf16x8 ah[4], al[4], bh[4], bl[4];
#pragma unroll
      for (int i = 0; i < 4; ++i) {
        int ar = qr * 64 + i * 16 + l15;
        int sa = ((kst * 4 + lg) ^ (ar & 7)) * 8;
        ah[i] = *(const bf16x8*)&AhS[ar][sa];
        al[i] = *(const bf16x8*)&AlS[ar][sa];
        int br = qc * 64 + i * 16 + l15;
        int sb = ((kst * 4 + lg) ^ (br & 7)) * 8;
        bh[i] = *(const bf16x8*)&BhS[br][sb];
        bl[i] = *(const bf16x8*)&BlS[br][sb];
      }
      __builtin_amdgcn_s_setprio(1);
#pragma unroll
      for (int i = 0; i < 4; ++i)
#pragma unroll
        for (int j = 0; j < 4; ++j) {
          acc[i][j] = __builtin_amdgcn_mfma_f32_16x16x32_bf16(ah[i], bh[j], acc[i][j], 0, 0, 0);
          acc[i][j] = __builtin_amdgcn_mfma_f32_16x16x32_bf16(al[i], bh[j], acc[i][j], 0, 0, 0);
          acc[i][j] = __builtin_amdgcn_mfma_f32_16x16x32_bf16(ah[i], bl[j], acc[i][j], 0, 0, 0);
        }
      __builtin_amdgcn_s_setprio(0);
    }
  }
#pragma unroll
  for (int i = 0; i < 4; ++i)
#pragma unroll
    for (int j = 0; j < 4; ++j) {
      int r0 = m0 + qr * 64 + i * 16 + lg * 4;
      int cc = n0 + qc * 64 + j * 16 + l15;
      if (z <= 1) {   // Q or K: [h][t][d] split hi/lo
        ushort* Chi = (z == 0) ? Qh : Kh;
        ushort* Clo = (z == 0) ? Ql : Kl;
        size_t o = (size_t)(cc >> 6) * Tq * HDC + (size_t)r0 * HDC + (cc & 63);
#pragma unroll
        for (int rg = 0; rg < 4; ++rg) {
          float v = acc[i][j][rg];
          ushort hh = f2bf(v);
          Chi[o + (size_t)rg * HDC] = hh;
          Clo[o + (size_t)rg * HDC] = f2bf(v - bf2f(hh));
        }
      } else {        // V: Vt[h][d][t] hi only
        bf16x4 ph;
#pragma unroll
        for (int rg = 0; rg < 4; ++rg) ph[rg] = (short)f2bf(acc[i][j][rg]);
        size_t o = (size_t)(cc >> 6) * HDC * Tq + (size_t)(cc & 63) * Tq + r0;
        *(bf16x4*)&Vth[o] = ph;
      }
    }
}

// ---------------------------------------------------------------------------
// Output projection: 128x64 tile, 8 waves. grid (16,16) = 256 blocks.
// ---------------------------------------------------------------------------
__global__ __launch_bounds__(512) void gemm_out(
    const ushort* __restrict__ Ah, const ushort* __restrict__ Al,
    const ushort* __restrict__ Bh, const ushort* __restrict__ Bl,
    float* __restrict__ Cf) {
  __shared__ ushort AhS[128][64], AlS[128][64], BhS[64][64], BlS[64][64];
  int tid = threadIdx.x;
  int w = tid >> 6, l = tid & 63, l15 = l & 15, lg = l >> 4;
  int wr = w >> 1, wc = w & 1;
  int lrow = l >> 3, lc8 = l & 7;
  int m0 = blockIdx.y * 128, n0 = blockIdx.x * 64;
  f32x4 acc[2][2] = {};
  for (int k0 = 0; k0 < Dm; k0 += 64) {
    __syncthreads();
#pragma unroll
    for (int hh = 0; hh < 2; ++hh) {
      int row = 16 * w + hh * 8 + lrow;
      size_t ao = (size_t)(m0 + row) * Dm + k0 + ((lc8 ^ (row & 7)) * 8);
      gload16(&Ah[ao], &AhS[16 * w + hh * 8][0]);
      gload16(&Al[ao], &AlS[16 * w + hh * 8][0]);
    }
    {
      int row = 8 * w + lrow;
      size_t bo = (size_t)(n0 + row) * Dm + k0 + ((lc8 ^ (row & 7)) * 8);
      gload16(&Bh[bo], &BhS[8 * w][0]);
      gload16(&Bl[bo], &BlS[8 * w][0]);
    }
    __syncthreads();
#pragma unroll
    for (int kst = 0; kst < 2; ++kst) {
      bf16x8 ah[2], al[2], bh[2], bl[2];
#pragma unroll
      for (int i = 0; i < 2; ++i) {
        int ar = wr * 32 + i * 16 + l15;
        int sa = ((kst * 4 + lg) ^ (ar & 7)) * 8;
        ah[i] = *(const bf16x8*)&AhS[ar][sa];
        al[i] = *(const bf16x8*)&AlS[ar][sa];
        int br = wc * 32 + i * 16 + l15;
        int sb = ((kst * 4 + lg) ^ (br & 7)) * 8;
        bh[i] = *(const bf16x8*)&BhS[br][sb];
        bl[i] = *(const bf16x8*)&BlS[br][sb];
      }
#pragma unroll
      for (int i = 0; i < 2; ++i)
#pragma unroll
        for (int j = 0; j < 2; ++j) {
          acc[i][j] = __builtin_amdgcn_mfma_f32_16x16x32_bf16(ah[i], bh[j], acc[i][j], 0, 0, 0);
          acc[i][j] = __builtin_amdgcn_mfma_f32_16x16x32_bf16(al[i], bh[j], acc[i][j], 0, 0, 0);
          acc[i][j] = __builtin_amdgcn_mfma_f32_16x16x32_bf16(ah[i], bl[j], acc[i][j], 0, 0, 0);
        }
    }
  }
#pragma unroll
  for (int i = 0; i < 2; ++i)
#pragma unroll
    for (int j = 0; j < 2; ++j) {
      int r0 = m0 + wr * 32 + i * 16 + lg * 4;
      int cc = n0 + wc * 32 + j * 16 + l15;
#pragma unroll
      for (int rg = 0; rg < 4; ++rg)
        Cf[(size_t)(r0 + rg) * Dm + cc] = acc[i][j][rg];
    }
}

// ---------------------------------------------------------------------------
// Downsampled scores from dense Qd/Kd (exact fp32 mask path).
// 32-row q-tiles -> grid (4,8,16) = 512 blocks (2/CU). Per-output k-chain
// (k=0..63 sequential) unchanged -> bit-identical values.
// ---------------------------------------------------------------------------
__global__ __launch_bounds__(256) void sd_kernel(
    const float* __restrict__ Qd, const float* __restrict__ Kd,
    float* __restrict__ Sd) {
  __shared__ float Qs[64][36];   // [k][i], i=32 (+4 pad)
  __shared__ float Ks[64][68];   // [k][j], j=64 (+4 pad)
  int jk0 = blockIdx.x * 64, iq0 = blockIdx.y * 32, h = blockIdx.z;
  int tid = threadIdx.x, tx = tid & 15, ty = tid >> 4;
#pragma unroll
  for (int q = 0; q < 2; ++q) {          // Q: 512 float4, 2/thread
    int f = tid * 2 + q;
    int row = f >> 4, c4 = f & 15;
    float4 q4 = *(const float4*)&Qd[(size_t)(iq0 + row) * Dm + h * HDC + c4 * 4];
    Qs[c4 * 4 + 0][row] = q4.x; Qs[c4 * 4 + 1][row] = q4.y;
    Qs[c4 * 4 + 2][row] = q4.z; Qs[c4 * 4 + 3][row] = q4.w;
  }
#pragma unroll
  for (int q = 0; q < 4; ++q) {          // K: 1024 float4, 4/thread
    int f = tid * 4 + q;
    int row = f >> 4, c4 = f & 15;
    float4 k4 = *(const float4*)&Kd[(size_t)(jk0 + row) * Dm + h * HDC + c4 * 4];
    Ks[c4 * 4 + 0][row] = k4.x; Ks[c4 * 4 + 1][row] = k4.y;
    Ks[c4 * 4 + 2][row] = k4.z; Ks[c4 * 4 + 3][row] = k4.w;
  }
  __syncthreads();
  float acc[2][4] = {};
#pragma unroll
  for (int k = 0; k < 64; ++k) {
    float a[2], b[4];
#pragma unroll
    for (int i = 0; i < 2; ++i) a[i] = Qs[k][ty * 2 + i];
#pragma unroll
    for (int j = 0; j < 4; ++j) b[j] = Ks[k][tx * 4 + j];
#pragma unroll
    for (int i = 0; i < 2; ++i)
#pragma unroll
      for (int j = 0; j < 4; ++j) acc[i][j] += a[i] * b[j];
  }
#pragma unroll
  for (int i = 0; i < 2; ++i)
#pragma unroll
    for (int j = 0; j < 4; ++j)
      Sd[(size_t)(h * TDC + iq0 + ty * 2 + i) * TDC + jk0 + tx * 4 + j] =
          acc[i][j] * 0.125f;
}

// ---------------------------------------------------------------------------
// FUSED: blk<1024 -> 26th-largest of 4 Sd rows; blk==1024 -> xmean2.
// ---------------------------------------------------------------------------
__global__ __launch_bounds__(256) void fused_kth_xm(
    const float* __restrict__ Sd, float* __restrict__ kth,
    const float* __restrict__ xp, float* __restrict__ xm) {
  int blk = blockIdx.x, tid = threadIdx.x;
  if (blk < 1024) {
    int lane = tid & 63;
    int b = blk * 4 + (tid >> 6);
    const float* row = &Sd[(size_t)b * TDC];
    float v[4];
#pragma unroll
    for (int j = 0; j < 4; ++j) v[j] = row[lane + 64 * j];
    float ans = 0.f;
    for (int it = 0; it < KSEL; ++it) {
      float lm = fmaxf(fmaxf(v[0], v[1]), fmaxf(v[2], v[3]));
#pragma unroll
      for (int off = 1; off < 64; off <<= 1) lm = fmaxf(lm, __shfl_xor(lm, off));
      if (it == KSEL - 1) { ans = lm; break; }
      unsigned long long ball =
          __ballot(v[0] == lm || v[1] == lm || v[2] == lm || v[3] == lm);
      int first = __ffsll(ball) - 1;
      if (lane == first) {
        if (v[0] == lm) v[0] = -INFINITY;
        else if (v[1] == lm) v[1] = -INFINITY;
        else if (v[2] == lm) v[2] = -INFINITY;
        else v[3] = -INFINITY;
      }
    }
    if (lane == 0) kth[b] = ans;
  } else {
    float4 s = {0.f, 0.f, 0.f, 0.f};
    for (int i = 0; i < 64; ++i) {
      float4 v = *(const float4*)&xp[i * Dm + tid * 4];
      s.x += v.x; s.y += v.y; s.z += v.z; s.w += v.w;
    }
    float4 o = {s.x * (1.f / 2048.f), s.y * (1.f / 2048.f),
                s.z * (1.f / 2048.f), s.w * (1.f / 2048.f)};
    *(float4*)&xm[tid * 4] = o;
  }
}

// ---------------------------------------------------------------------------
// FUSED: pidx<1280 -> split-j flash attention partial (swapped QK^T,
// gload_lds staging, defer-rescale, shared pen_s, setprio around MFMA
// clusters); pidx>=1280 -> vm (Vmean = xm @ wv^T).
// ---------------------------------------------------------------------------
__global__ __launch_bounds__(256) void fused_attn_vm(
    const ushort* __restrict__ Qh, const ushort* __restrict__ Ql,
    const ushort* __restrict__ Kh, const ushort* __restrict__ Kl,
    const ushort* __restrict__ Vth, const float* __restrict__ U,
    const float* __restrict__ Sd, const float* __restrict__ kth,
    const float* __restrict__ xm, const float* __restrict__ wv,
    float* __restrict__ Vm,
    ushort* __restrict__ Pacc, float* __restrict__ Pm, float* __restrict__ Pl) {
  int pidx = blockIdx.x;
  int tid = threadIdx.x;
  if (pidx >= 1280) {   // vm blocks
    int h = pidx - 1280;
    int r = h * 64 + (tid >> 2), q = tid & 3;
    const float* wrow = wv + (size_t)r * Dm + q * 256;
    const float* a = xm + q * 256;
    float s = 0.f;
    for (int k = 0; k < 256; k += 4) {
      float4 w4 = *(const float4*)&wrow[k];
      float4 a4 = *(const float4*)&a[k];
      s += w4.x * a4.x + w4.y * a4.y + w4.z * a4.z + w4.w * a4.w;
    }
    s += __shfl_xor(s, 1); s += __shfl_xor(s, 2);
    if (q == 0) Vm[r] = s;
    return;
  }
  int xcd = pidx & 7, idx = pidx >> 3;
  int h = xcd * 2 + (idx & 1);
  int p = idx >> 1;                       // 0..79 active (c,qt) pairs
  int c, qt;
  if (p < 32)      { c = 0; qt = p; }
  else if (p < 56) { c = 1; qt = p - 24; }
  else if (p < 72) { c = 2; qt = p - 40; }
  else             { c = 3; qt = p - 48; }
  int w = tid >> 6, l = tid & 63, l15 = l & 15, lg = l >> 4;
  int lrow = l >> 3, lc8 = l & 7;        // staging roles
  int i0 = qt * 64;
  int irow = i0 + 16 * w + l15;          // this lane's q-row
  int rloc = 16 * w + l15;               // row within tile

  __shared__ ushort KhS[64][64], KlS[64][64], VhS[64][64];
  __shared__ ushort Ps[4][16][72];
  __shared__ float pen_s[64][9];          // pad 9 -> conflict-free reads

  // pen-producer role: this thread computes pens for (prow, pjb..pjb+1)
  int prow = tid >> 2;                    // 0..63
  int pjb  = (tid & 3) * 2;               // 0,2,4,6
  float puu; { float t = U[i0 + prow]; puu = 1.f + fminf(fmaxf(t, 0.f), 1.f); }
  int pi8 = (i0 + prow) >> 3;
  float pkvu = kth[h * TDC + pi8] * puu;  // fl(kv*u), matches reference
  const float* pSdRow = Sd + ((size_t)h * TDC + pi8) * TDC;

  size_t qoff = ((size_t)h * Tq + irow) * HDC;
  bf16x8 qh0 = *(const bf16x8*)(Qh + qoff + lg * 8);
  bf16x8 qh1 = *(const bf16x8*)(Qh + qoff + 32 + lg * 8);
  bf16x8 ql0 = *(const bf16x8*)(Ql + qoff + lg * 8);
  bf16x8 ql1 = *(const bf16x8*)(Ql + qoff + 32 + lg * 8);

  float mrow = -INFINITY, lrow_acc = 0.f;
  f32x4 acc[4] = {};

  int jt1 = min(c * CH + CH, qt + 1);
  for (int jt = c * CH; jt < jt1; ++jt) {
    int j0 = jt * 64;
    __syncthreads();
    // async stage K hi/lo + V
#pragma unroll
    for (int hh = 0; hh < 2; ++hh) {
      int row = 16 * w + hh * 8 + lrow;
      int scol = (lc8 ^ (row & 7)) * 8;
      size_t ko = ((size_t)h * Tq + j0 + row) * HDC + scol;
      size_t vo = ((size_t)h * HDC + row) * Tq + j0 + scol;
      gload16(&Kh[ko], &KhS[16 * w + hh * 8][0]);
      gload16(&Kl[ko], &KlS[16 * w + hh * 8][0]);
      gload16(&Vth[vo], &VhS[16 * w + hh * 8][0]);
    }

    // shared pen production (exact fp32 reference op order) — overlaps loads
    {
      int jbase = j0 >> 3;
#pragma unroll
      for (int q = 0; q < 2; ++q) {
        float sdv = pSdRow[jbase + pjb + q];
        float arg = (sdv * puu - pkvu) * 10.f;
        float mk;
        if (arg >= 0.f) mk = 1.f / (1.f + expf(-arg));
        else { float e = expf(arg); mk = e / (1.f + e); }
        pen_s[prow][pjb + q] = (1.f - mk) * (-1.0e9f);
      }
    }
    __syncthreads();   // drains vmcnt -> staged K/V + pen_s visible

    // S^T = K Q^T (split: 24 MFMA). Lane holds S[irow][j0+nt*16+lg*4+rg].
    f32x4 s[4] = {};
    __builtin_amdgcn_s_setprio(1);
#pragma unroll
    for (int nt = 0; nt < 4; ++nt) {
      int kr = nt * 16 + l15;
      int s0 = ((0 + lg) ^ (kr & 7)) * 8;
      int s1 = ((4 + lg) ^ (kr & 7)) * 8;
      bf16x8 ah0 = *(const bf16x8*)&KhS[kr][s0];
      bf16x8 ah1 = *(const bf16x8*)&KhS[kr][s1];
      bf16x8 al0 = *(const bf16x8*)&KlS[kr][s0];
      bf16x8 al1 = *(const bf16x8*)&KlS[kr][s1];
      s[nt] = __builtin_amdgcn_mfma_f32_16x16x32_bf16(ah0, qh0, s[nt], 0, 0, 0);
      s[nt] = __builtin_amdgcn_mfma_f32_16x16x32_bf16(ah1, qh1, s[nt], 0, 0, 0);
      s[nt] = __builtin_amdgcn_mfma_f32_16x16x32_bf16(al0, qh0, s[nt], 0, 0, 0);
      s[nt] = __builtin_amdgcn_mfma_f32_16x16x32_bf16(al1, qh1, s[nt], 0, 0, 0);
      s[nt] = __builtin_amdgcn_mfma_f32_16x16x32_bf16(ah0, ql0, s[nt], 0, 0, 0);
      s[nt] = __builtin_amdgcn_mfma_f32_16x16x32_bf16(ah1, ql1, s[nt], 0, 0, 0);
    }
    __builtin_amdgcn_s_setprio(0);

    // pens from LDS (values identical to per-lane computation)
    float pen[4];
#pragma unroll
    for (int nt = 0; nt < 4; ++nt) pen[nt] = pen_s[rloc][nt * 2 + (lg >> 1)];

    // logits + in-lane online softmax for row irow
    bool diag = (jt == qt);
    float lgv[4][4];
    float tmax = -INFINITY;
    if (diag) {
#pragma unroll
      for (int nt = 0; nt < 4; ++nt)
#pragma unroll
        for (int rg = 0; rg < 4; ++rg) {
          int jj = j0 + nt * 16 + lg * 4 + rg;
          float lv = s[nt][rg] * 0.125f + ((jj > irow) ? -1.0e9f : pen[nt]);
          lgv[nt][rg] = lv;
          tmax = fmaxf(tmax, lv);
        }
    } else {
#pragma unroll
      for (int nt = 0; nt < 4; ++nt)
#pragma unroll
        for (int rg = 0; rg < 4; ++rg) {
          float lv = s[nt][rg] * 0.125f + pen[nt];
          lgv[nt][rg] = lv;
          tmax = fmaxf(tmax, lv);
        }
    }
    tmax = fmaxf(tmax, __shfl_xor(tmax, 16));
    tmax = fmaxf(tmax, __shfl_xor(tmax, 32));
    float mnew = fmaxf(mrow, tmax);
    float ps = 0.f;
#pragma unroll
    for (int nt = 0; nt < 4; ++nt) {
      float p0 = __expf(lgv[nt][0] - mnew);
      float p1 = __expf(lgv[nt][1] - mnew);
      float p2 = __expf(lgv[nt][2] - mnew);
      float p3 = __expf(lgv[nt][3] - mnew);
      ps += (p0 + p1) + (p2 + p3);        // fp32 denominator
      uint2 pk;
      asm("v_cvt_pk_bf16_f32 %0, %1, %2" : "=v"(pk.x) : "v"(p0), "v"(p1));
      asm("v_cvt_pk_bf16_f32 %0, %1, %2" : "=v"(pk.y) : "v"(p2), "v"(p3));
      *(uint2*)&Ps[w][l15][nt * 16 + lg * 4] = pk;
    }
    ps += __shfl_xor(ps, 16);
    ps += __shfl_xor(ps, 32);
    // defer-rescale: when no lane's max advanced, sc==1.0 exactly ->
    // skipping the rescale is bit-identical.
    if (!__all(tmax <= mrow)) {
      float sc = __expf(mrow - mnew);     // exp(-inf)=0 on first tile
      lrow_acc = lrow_acc * sc + ps;
      mrow = mnew;
      float scr[4];
#pragma unroll
      for (int rg = 0; rg < 4; ++rg) scr[rg] = __shfl(sc, lg * 4 + rg);
#pragma unroll
      for (int ntd = 0; ntd < 4; ++ntd)
#pragma unroll
        for (int rg = 0; rg < 4; ++rg) acc[ntd][rg] *= scr[rg];
    } else {
      lrow_acc += ps;
    }

    // O += P V  (hi-only V: 8 MFMA)
    __builtin_amdgcn_s_setprio(1);
#pragma unroll
    for (int kst = 0; kst < 2; ++kst) {
      bf16x8 pa = *(const bf16x8*)&Ps[w][l15][kst * 32 + lg * 8];
#pragma unroll
      for (int ntd = 0; ntd < 4; ++ntd) {
        int vr = ntd * 16 + l15;
        int sv = ((kst * 4 + lg) ^ (vr & 7)) * 8;
        bf16x8 vbh = *(const bf16x8*)&VhS[vr][sv];
        acc[ntd] = __builtin_amdgcn_mfma_f32_16x16x32_bf16(pa, vbh, acc[ntd], 0, 0, 0);
      }
    }
    __builtin_amdgcn_s_setprio(0);
  }

  size_t rowbase = ((size_t)c * NHC + h) * Tq + i0 + 16 * w;
  if (lg == 0) {
    Pm[rowbase + l15] = mrow;
    Pl[rowbase + l15] = lrow_acc;
  }
#pragma unroll
  for (int ntd = 0; ntd < 4; ++ntd)
#pragma unroll
    for (int rg = 0; rg < 4; ++rg)
      Pacc[(rowbase + lg * 4 + rg) * HDC + ntd * 16 + l15] = f2bf(acc[ntd][rg]);
}

// ---------------------------------------------------------------------------
// Merge split-j partials -> AO split bf16 hi/lo [t][1024]  (untouched)
// ---------------------------------------------------------------------------
__global__ __launch_bounds__(256) void attn_merge(
    const ushort* __restrict__ Pacc, const float* __restrict__ Pm,
    const float* __restrict__ Pl, const float* __restrict__ Vm,
    ushort* __restrict__ AOh, ushort* __restrict__ AOl) {
  int qt = blockIdx.x, h = blockIdx.y;
  int tid = threadIdx.x;
  int r = tid >> 2, q4 = tid & 3;
  int gi = qt * 64 + r;
  int nc = (qt >> 3) + 1;
  float M = -INFINITY, mv[4];
#pragma unroll
  for (int cc = 0; cc < 4; ++cc) {
    mv[cc] = (cc < nc) ? Pm[((size_t)cc * NHC + h) * Tq + gi] : -INFINITY;
    M = fmaxf(M, mv[cc]);
  }
  if (M == -1.0e9f) {   // all-masked: reference softmax uniform over ALL rows
#pragma unroll
    for (int dd = 0; dd < 16; dd += 4) {
      int d = q4 * 16 + dd;
      float4 v = *(const float4*)&Vm[h * HDC + d];
      float vv[4] = {v.x, v.y, v.z, v.w};
      ushort4 uh, ul;
      ushort* uhp = &uh.x; ushort* ulp = &ul.x;
#pragma unroll
      for (int j = 0; j < 4; ++j) {
        ushort hh = f2bf(vv[j]);
        uhp[j] = hh; ulp[j] = f2bf(vv[j] - bf2f(hh));
      }
      *(ushort4*)&AOh[(size_t)gi * Dm + h * HDC + d] = uh;
      *(ushort4*)&AOl[(size_t)gi * Dm + h * HDC + d] = ul;
    }
    return;
  }
  float W[4], L = 0.f;
#pragma unroll
  for (int cc = 0; cc < 4; ++cc) {
    W[cc] = (cc < nc) ? __expf(mv[cc] - M) : 0.f;
    if (cc < nc) L += Pl[((size_t)cc * NHC + h) * Tq + gi] * W[cc];
  }
  float invL = 1.f / L;
#pragma unroll
  for (int dd = 0; dd < 16; dd += 4) {
    int d = q4 * 16 + dd;
    float o[4] = {0.f, 0.f, 0.f, 0.f};
    for (int cc = 0; cc < nc; ++cc) {
      bf16x4 a = *(const bf16x4*)&Pacc[(((size_t)cc * NHC + h) * Tq + gi) * HDC + d];
#pragma unroll
      for (int j = 0; j < 4; ++j) o[j] += bf2f((ushort)a[j]) * W[cc];
    }
    ushort4 uh, ul;
    ushort* uhp = &uh.x; ushort* ulp = &ul.x;
#pragma unroll
    for (int j = 0; j < 4; ++j) {
      float vv = o[j] * invL;
      ushort hh = f2bf(vv);
      uhp[j] = hh; ulp[j] = f2bf(vv - bf2f(hh));
    }
    *(ushort4*)&AOh[(size_t)gi * Dm + h * HDC + d] = uh;
    *(ushort4*)&AOl[(size_t)gi * Dm + h * HDC + d] = ul;
  }
}

// ---------------------------------------------------------------------------
extern "C" void kernel_launch(void* const* d_in, const int* in_sizes, int n_in,
                              void* d_out, int out_size, void* d_ws, size_t ws_size,
                              hipStream_t stream) {
  const float* x  = (const float*)d_in[0];
  const float* U  = (const float*)d_in[1];
  const float* wq = (const float*)d_in[2];
  const float* wk = (const float*)d_in[3];
  const float* wv = (const float*)d_in[4];
  const float* wo = (const float*)d_in[5];
  float* out = (float*)d_out;

  float* fw = (float*)d_ws;
  const size_t TD_ = (size_t)Tq * Dm;          // 2M elements
  const size_t WW_ = (size_t)Dm * Dm;          // 1M elements
  const size_t QD_ = (size_t)TDC * Dm;         // 256K elements
  float* Qd  = fw;                 fw += QD_;
  float* Kd  = fw;                 fw += QD_;
  float* Sd  = fw;                 fw += (size_t)NHC * TDC * TDC;
  float* kth = fw;                 fw += 4096;
  float* Vm  = fw;                 fw += 4096;
  float* xm  = fw;                 fw += 4096;
  float* xp  = fw;                 fw += 64 * Dm;
  float* Pm  = fw;                 fw += 4 * NHC * Tq;
  float* Pl  = fw;                 fw += 4 * NHC * Tq;
  ushort* uw = (ushort*)fw;
  ushort* xh   = uw;               uw += TD_;
  ushort* xl   = uw;               uw += TD_;
  ushort* wqh  = uw;               uw += WW_;
  ushort* wql  = uw;               uw += WW_;
  ushort* wkh  = uw;               uw += WW_;
  ushort* wkl  = uw;               uw += WW_;
  ushort* wvh  = uw;               uw += WW_;
  ushort* wvl  = uw;               uw += WW_;
  ushort* woh  = uw;               uw += WW_;
  ushort* wol  = uw;               uw += WW_;
  ushort* Qh   = uw;               uw += TD_;
  ushort* Ql   = uw;               uw += TD_;
  ushort* Kh   = uw;               uw += TD_;
  ushort* Kl   = uw;               uw += TD_;
  ushort* Vth  = uw;               uw += TD_;
  ushort* Pacc = uw;               uw += (size_t)4 * NHC * Tq * HDC;
  // AO aliases x's split buffers (lifetimes disjoint)
  ushort* AOh = xh;
  ushort* AOl = xl;

  dim3 bb(256);
  // 1) fused splits (flat grid)
  cast_split_all<<<dim3(6144), bb, 0, stream>>>(
      x, wq, wk, wv, wo, xh, xl, wqh, wql, wkh, wkl, wvh, wvl, woh, wol);
  // 2) ALL projection GEMMs, exactly 512 blocks (qkd+xpart first, qkv swizzled)
  fused_gemms<<<dim3(512), bb, 0, stream>>>(
      x, wq, wk, Qd, Kd, xp,
      xh, xl, wqh, wql, wkh, wkl, wvh, wvl, Qh, Ql, Kh, Kl, Vth);
  // 3) mask scores (exact fp32), 512 blocks
  sd_kernel<<<dim3(4, 8, NHC), bb, 0, stream>>>(Qd, Kd, Sd);
  // 4) fused: kth selection + xmean2
  fused_kth_xm<<<dim3(1025), bb, 0, stream>>>(Sd, kth, xp, xm);
  // 5) fused: split-j flash attention (shared pen_s, setprio) + vm
  fused_attn_vm<<<dim3(1296), bb, 0, stream>>>(
      Qh, Ql, Kh, Kl, Vth, U, Sd, kth, xm, wv, Vm, Pacc, Pm, Pl);
  // 6) merge partials
  attn_merge<<<dim3(Tq / 64, NHC), bb, 0, stream>>>(Pacc, Pm, Pl, Vm, AOh, AOl);
  // 7) output projection (128x64, 256 blocks -> 1/CU)
  gemm_out<<<dim3(16, 16), dim3(512), 0, stream>>>(AOh, AOl, woh, wol, out);
}

// Round 18
// 167.354 us; speedup vs baseline: 1.0150x; 1.0150x over previous
//
#include <hip/hip_runtime.h>
#include <hip/hip_bf16.h>
#include <cmath>

typedef __attribute__((ext_vector_type(8))) short bf16x8;
typedef __attribute__((ext_vector_type(4))) short bf16x4;
typedef __attribute__((ext_vector_type(4))) float f32x4;

constexpr int Tq  = 2048;
constexpr int Dm  = 1024;
constexpr int NHC = 16;
constexpr int HDC = 64;
constexpr int TDC = 256;
constexpr int KSEL = 26;   // ceil(204/8): 26th-largest distinct value
constexpr int CH  = 8;     // j-tiles (of 64) per split-j chunk

__device__ inline ushort f2bf(float x) {
  union { float f; unsigned u; } v; v.f = x;
  return (ushort)((v.u + 0x7FFF + ((v.u >> 16) & 1)) >> 16);
}
__device__ inline float bf2f(ushort b) {
  union { unsigned u; float f; } v; v.u = ((unsigned)b) << 16;
  return v.f;
}
// async global->LDS, 16B per lane; LDS dest = wave-uniform base + lane*16
__device__ inline void gload16(const ushort* g, ushort* l) {
  __builtin_amdgcn_global_load_lds(
      (const __attribute__((address_space(1))) unsigned int*)g,
      (__attribute__((address_space(3))) unsigned int*)l, 16, 0, 0);
}

// ---------------------------------------------------------------------------
// Fused split-cast of x + 4 weight matrices, flat 1D grid (6144 blocks).
// ---------------------------------------------------------------------------
__global__ __launch_bounds__(256) void cast_split_all(
    const float* __restrict__ x,  const float* __restrict__ wq,
    const float* __restrict__ wk, const float* __restrict__ wv,
    const float* __restrict__ wo,
    ushort* __restrict__ xh,  ushort* __restrict__ xl,
    ushort* __restrict__ wqh, ushort* __restrict__ wql,
    ushort* __restrict__ wkh, ushort* __restrict__ wkl,
    ushort* __restrict__ wvh, ushort* __restrict__ wvl,
    ushort* __restrict__ woh, ushort* __restrict__ wol) {
  int bid = blockIdx.x;
  const float* src; ushort *hi, *lo; int blk;
  if (bid < 2048)      { src = x;  hi = xh;  lo = xl;  blk = bid; }
  else {
    int z = (bid - 2048) >> 10;
    blk = (bid - 2048) & 1023;
    if (z == 0)      { src = wq; hi = wqh; lo = wql; }
    else if (z == 1) { src = wk; hi = wkh; lo = wkl; }
    else if (z == 2) { src = wv; hi = wvh; lo = wvl; }
    else             { src = wo; hi = woh; lo = wol; }
  }
  int base = (blk * 256 + threadIdx.x) * 4;
  float4 v = *(const float4*)&src[base];
  ushort h0 = f2bf(v.x), h1 = f2bf(v.y), h2 = f2bf(v.z), h3 = f2bf(v.w);
  *(ushort4*)&hi[base] = make_ushort4(h0, h1, h2, h3);
  *(ushort4*)&lo[base] = make_ushort4(
      f2bf(v.x - bf2f(h0)), f2bf(v.y - bf2f(h1)),
      f2bf(v.z - bf2f(h2)), f2bf(v.w - bf2f(h3)));
}

// ---------------------------------------------------------------------------
// FUSED GEMM launch, 1D grid of EXACTLY 512 blocks (2/CU), 64KB LDS:
//   bid <  128 : exact fp32 Qd/Kd GEMM (BK=16 dbuf body, bit-identical);
//                blocks 0..63 additionally run xpart AFTER the GEMM.
//   bid >= 128 : 128x128 split-bf16 MFMA Q/K/V GEMM, XCD-swizzled.
// ---------------------------------------------------------------------------
__global__ __launch_bounds__(256, 2) void fused_gemms(
    const float* __restrict__ x, const float* __restrict__ wq,
    const float* __restrict__ wk, float* __restrict__ Qd,
    float* __restrict__ Kd, float* __restrict__ xp,
    const ushort* __restrict__ xh_, const ushort* __restrict__ xl_,
    const ushort* __restrict__ wqh_, const ushort* __restrict__ wql_,
    const ushort* __restrict__ wkh_, const ushort* __restrict__ wkl_,
    const ushort* __restrict__ wvh_, const ushort* __restrict__ wvl_,
    ushort* __restrict__ Qh, ushort* __restrict__ Ql,
    ushort* __restrict__ Kh, ushort* __restrict__ Kl,
    ushort* __restrict__ Vth) {
  __shared__ __align__(16) char smem[65536];
  int bid = blockIdx.x;
  int tid = threadIdx.x;
  if (bid < 128) {
    // ---- exact fp32 Qd/Kd (mask path), 64x64 tile, BK=16 double-buffered ----
    int mat = bid >> 6;
    int rem = bid & 63;
    int n0 = (rem & 15) * 64, m0 = (rem >> 4) * 64;
    const float* B = mat ? wk : wq;
    float* C = mat ? Kd : Qd;
    typedef float lds16x68[16][68];
    lds16x68* As = (lds16x68*)(smem);                       // [2][16][68]
    lds16x68* Bs = (lds16x68*)(smem + 2 * 16 * 68 * 4);     // [2][16][68]
    int tx = tid & 15, ty = tid >> 4;
    int srow = tid >> 2, sc4 = tid & 3;
    const float* Arow = &x[(size_t)((m0 + srow) * 8) * 1024 + sc4 * 4];
    const float* Brow = &B[(size_t)(n0 + srow) * 1024 + sc4 * 4];
    float acc[4][4] = {};
    {
      float4 av = *(const float4*)&Arow[0];
      float4 bv = *(const float4*)&Brow[0];
      As[0][sc4 * 4 + 0][srow] = av.x; As[0][sc4 * 4 + 1][srow] = av.y;
      As[0][sc4 * 4 + 2][srow] = av.z; As[0][sc4 * 4 + 3][srow] = av.w;
      Bs[0][sc4 * 4 + 0][srow] = bv.x; Bs[0][sc4 * 4 + 1][srow] = bv.y;
      Bs[0][sc4 * 4 + 2][srow] = bv.z; Bs[0][sc4 * 4 + 3][srow] = bv.w;
    }
    __syncthreads();
    for (int iter = 0; iter < 64; ++iter) {
      int cbuf = iter & 1, nbuf = cbuf ^ 1;
      bool hn = (iter + 1 < 64);
      float4 av, bv;
      if (hn) {
        int k0 = (iter + 1) * 16;
        av = *(const float4*)&Arow[k0];
        bv = *(const float4*)&Brow[k0];
      }
#pragma unroll
      for (int k = 0; k < 16; ++k) {
        float a[4], b[4];
#pragma unroll
        for (int i = 0; i < 4; ++i) {
          a[i] = As[cbuf][k][ty * 4 + i];
          b[i] = Bs[cbuf][k][tx * 4 + i];
        }
#pragma unroll
        for (int i = 0; i < 4; ++i)
#pragma unroll
          for (int j = 0; j < 4; ++j) acc[i][j] += a[i] * b[j];
      }
      if (hn) {
        As[nbuf][sc4 * 4 + 0][srow] = av.x; As[nbuf][sc4 * 4 + 1][srow] = av.y;
        As[nbuf][sc4 * 4 + 2][srow] = av.z; As[nbuf][sc4 * 4 + 3][srow] = av.w;
        Bs[nbuf][sc4 * 4 + 0][srow] = bv.x; Bs[nbuf][sc4 * 4 + 1][srow] = bv.y;
        Bs[nbuf][sc4 * 4 + 2][srow] = bv.z; Bs[nbuf][sc4 * 4 + 3][srow] = bv.w;
      }
      __syncthreads();
    }
#pragma unroll
    for (int i = 0; i < 4; ++i)
#pragma unroll
      for (int j = 0; j < 4; ++j)
        C[(size_t)(m0 + ty * 4 + i) * 1024 + n0 + tx * 4 + j] = acc[i][j];
    // ---- blocks 0..63 append xpart (verbatim per-thread code) ----
    if (bid < 64) {
      int b = bid;
      float4 s = {0.f, 0.f, 0.f, 0.f};
      for (int r = 0; r < 32; ++r) {
        float4 v = *(const float4*)&x[(size_t)(b * 32 + r) * Dm + tid * 4];
        s.x += v.x; s.y += v.y; s.z += v.z; s.w += v.w;
      }
      *(float4*)&xp[b * Dm + tid * 4] = s;
    }
    return;
  }
  // ---- 128x128 split-bf16 MFMA Q/K/V, XCD-swizzled (bit-identical body) ----
  int q_ = bid - 128;                 // 0..383, 384 % 8 == 0
  int xcd = q_ & 7, j_ = q_ >> 3;     // j_ 0..47
  int panel = xcd * 3 + (j_ >> 4);    // 0..23: (z, n_t) panel
  int m_t = j_ & 15;
  int z = panel >> 3, n_t = panel & 7;
  int n0 = n_t * 128, m0 = m_t * 128;
  const ushort* Bhp = (z == 0) ? wqh_ : ((z == 1) ? wkh_ : wvh_);
  const ushort* Blp = (z == 0) ? wql_ : ((z == 1) ? wkl_ : wvl_);
  ushort (*AhS)[64] = (ushort(*)[64])(smem);
  ushort (*AlS)[64] = (ushort(*)[64])(smem + 16384);
  ushort (*BhS)[64] = (ushort(*)[64])(smem + 32768);
  ushort (*BlS)[64] = (ushort(*)[64])(smem + 49152);
  int w = tid >> 6, l = tid & 63, l15 = l & 15, lg = l >> 4;
  int qr = w >> 1, qc = w & 1;
  int lrow = l >> 3, lc8 = l & 7;
  f32x4 acc[4][4] = {};
  for (int k0 = 0; k0 < Dm; k0 += 64) {
    __syncthreads();
#pragma unroll
    for (int s = 0; s < 4; ++s) {
      int row = 32 * w + s * 8 + lrow;
      int scol = (lc8 ^ (row & 7)) * 8;
      size_t ao = (size_t)(m0 + row) * Dm + k0 + scol;
      size_t bo = (size_t)(n0 + row) * Dm + k0 + scol;
      gload16(&xh_[ao], &AhS[32 * w + s * 8][0]);
      gload16(&xl_[ao], &AlS[32 * w + s * 8][0]);
      gload16(&Bhp[bo], &BhS[32 * w + s * 8][0]);
      gload16(&Blp[bo], &BlS[32 * w + s * 8][0]);
    }
    __syncthreads();
#pragma unroll
    for (int kst = 0; kst < 2; ++kst) {
      bf16x8 ah[4], al[4], bh[4], bl[4];
#pragma unroll
      for (int i = 0; i < 4; ++i) {
        int ar = qr * 64 + i * 16 + l15;
        int sa = ((kst * 4 + lg) ^ (ar & 7)) * 8;
        ah[i] = *(const bf16x8*)&AhS[ar][sa];
        al[i] = *(const bf16x8*)&AlS[ar][sa];
        int br = qc * 64 + i * 16 + l15;
        int sb = ((kst * 4 + lg) ^ (br & 7)) * 8;
        bh[i] = *(const bf16x8*)&BhS[br][sb];
        bl[i] = *(const bf16x8*)&BlS[br][sb];
      }
#pragma unroll
      for (int i = 0; i < 4; ++i)
#pragma unroll
        for (int j = 0; j < 4; ++j) {
          acc[i][j] = __builtin_amdgcn_mfma_f32_16x16x32_bf16(ah[i], bh[j], acc[i][j], 0, 0, 0);
          acc[i][j] = __builtin_amdgcn_mfma_f32_16x16x32_bf16(al[i], bh[j], acc[i][j], 0, 0, 0);
          acc[i][j] = __builtin_amdgcn_mfma_f32_16x16x32_bf16(ah[i], bl[j], acc[i][j], 0, 0, 0);
        }
    }
  }
#pragma unroll
  for (int i = 0; i < 4; ++i)
#pragma unroll
    for (int j = 0; j < 4; ++j) {
      int r0 = m0 + qr * 64 + i * 16 + lg * 4;
      int cc = n0 + qc * 64 + j * 16 + l15;
      if (z <= 1) {   // Q or K: [h][t][d] split hi/lo
        ushort* Chi = (z == 0) ? Qh : Kh;
        ushort* Clo = (z == 0) ? Ql : Kl;
        size_t o = (size_t)(cc >> 6) * Tq * HDC + (size_t)r0 * HDC + (cc & 63);
#pragma unroll
        for (int rg = 0; rg < 4; ++rg) {
          float v = acc[i][j][rg];
          ushort hh = f2bf(v);
          Chi[o + (size_t)rg * HDC] = hh;
          Clo[o + (size_t)rg * HDC] = f2bf(v - bf2f(hh));
        }
      } else {        // V: Vt[h][d][t] hi only
        bf16x4 ph;
#pragma unroll
        for (int rg = 0; rg < 4; ++rg) ph[rg] = (short)f2bf(acc[i][j][rg]);
        size_t o = (size_t)(cc >> 6) * HDC * Tq + (size_t)(cc & 63) * Tq + r0;
        *(bf16x4*)&Vth[o] = ph;
      }
    }
}

// ---------------------------------------------------------------------------
// Output projection: 128x64 tile, 8 waves. grid (16,16) = 256 blocks.
// ---------------------------------------------------------------------------
__global__ __launch_bounds__(512) void gemm_out(
    const ushort* __restrict__ Ah, const ushort* __restrict__ Al,
    const ushort* __restrict__ Bh, const ushort* __restrict__ Bl,
    float* __restrict__ Cf) {
  __shared__ ushort AhS[128][64], AlS[128][64], BhS[64][64], BlS[64][64];
  int tid = threadIdx.x;
  int w = tid >> 6, l = tid & 63, l15 = l & 15, lg = l >> 4;
  int wr = w >> 1, wc = w & 1;
  int lrow = l >> 3, lc8 = l & 7;
  int m0 = blockIdx.y * 128, n0 = blockIdx.x * 64;
  f32x4 acc[2][2] = {};
  for (int k0 = 0; k0 < Dm; k0 += 64) {
    __syncthreads();
#pragma unroll
    for (int hh = 0; hh < 2; ++hh) {
      int row = 16 * w + hh * 8 + lrow;
      size_t ao = (size_t)(m0 + row) * Dm + k0 + ((lc8 ^ (row & 7)) * 8);
      gload16(&Ah[ao], &AhS[16 * w + hh * 8][0]);
      gload16(&Al[ao], &AlS[16 * w + hh * 8][0]);
    }
    {
      int row = 8 * w + lrow;
      size_t bo = (size_t)(n0 + row) * Dm + k0 + ((lc8 ^ (row & 7)) * 8);
      gload16(&Bh[bo], &BhS[8 * w][0]);
      gload16(&Bl[bo], &BlS[8 * w][0]);
    }
    __syncthreads();
#pragma unroll
    for (int kst = 0; kst < 2; ++kst) {
      bf16x8 ah[2], al[2], bh[2], bl[2];
#pragma unroll
      for (int i = 0; i < 2; ++i) {
        int ar = wr * 32 + i * 16 + l15;
        int sa = ((kst * 4 + lg) ^ (ar & 7)) * 8;
        ah[i] = *(const bf16x8*)&AhS[ar][sa];
        al[i] = *(const bf16x8*)&AlS[ar][sa];
        int br = wc * 32 + i * 16 + l15;
        int sb = ((kst * 4 + lg) ^ (br & 7)) * 8;
        bh[i] = *(const bf16x8*)&BhS[br][sb];
        bl[i] = *(const bf16x8*)&BlS[br][sb];
      }
#pragma unroll
      for (int i = 0; i < 2; ++i)
#pragma unroll
        for (int j = 0; j < 2; ++j) {
          acc[i][j] = __builtin_amdgcn_mfma_f32_16x16x32_bf16(ah[i], bh[j], acc[i][j], 0, 0, 0);
          acc[i][j] = __builtin_amdgcn_mfma_f32_16x16x32_bf16(al[i], bh[j], acc[i][j], 0, 0, 0);
          acc[i][j] = __builtin_amdgcn_mfma_f32_16x16x32_bf16(ah[i], bl[j], acc[i][j], 0, 0, 0);
        }
    }
  }
#pragma unroll
  for (int i = 0; i < 2; ++i)
#pragma unroll
    for (int j = 0; j < 2; ++j) {
      int r0 = m0 + wr * 32 + i * 16 + lg * 4;
      int cc = n0 + wc * 32 + j * 16 + l15;
#pragma unroll
      for (int rg = 0; rg < 4; ++rg)
        Cf[(size_t)(r0 + rg) * Dm + cc] = acc[i][j][rg];
    }
}

// ---------------------------------------------------------------------------
// Downsampled scores from dense Qd/Kd (exact fp32 mask path, round-16 form)
// ---------------------------------------------------------------------------
__global__ __launch_bounds__(256) void sd_kernel(
    const float* __restrict__ Qd, const float* __restrict__ Kd,
    float* __restrict__ Sd) {
  __shared__ float Qs[64][68];
  __shared__ float Ks[64][68];
  int jk0 = blockIdx.x * 64, iq0 = blockIdx.y * 64, h = blockIdx.z;
  int tid = threadIdx.x, tx = tid & 15, ty = tid >> 4;
#pragma unroll
  for (int q = 0; q < 4; ++q) {
    int f = tid * 4 + q;
    int row = f >> 4, c4 = f & 15;
    float4 q4 = *(const float4*)&Qd[(size_t)(iq0 + row) * Dm + h * HDC + c4 * 4];
    float4 k4 = *(const float4*)&Kd[(size_t)(jk0 + row) * Dm + h * HDC + c4 * 4];
    Qs[c4 * 4 + 0][row] = q4.x; Qs[c4 * 4 + 1][row] = q4.y;
    Qs[c4 * 4 + 2][row] = q4.z; Qs[c4 * 4 + 3][row] = q4.w;
    Ks[c4 * 4 + 0][row] = k4.x; Ks[c4 * 4 + 1][row] = k4.y;
    Ks[c4 * 4 + 2][row] = k4.z; Ks[c4 * 4 + 3][row] = k4.w;
  }
  __syncthreads();
  float acc[4][4] = {};
#pragma unroll
  for (int k = 0; k < 64; ++k) {
    float a[4], b[4];
#pragma unroll
    for (int i = 0; i < 4; ++i) { a[i] = Qs[k][ty * 4 + i]; b[i] = Ks[k][tx * 4 + i]; }
#pragma unroll
    for (int i = 0; i < 4; ++i)
#pragma unroll
      for (int j = 0; j < 4; ++j) acc[i][j] += a[i] * b[j];
  }
#pragma unroll
  for (int i = 0; i < 4; ++i)
#pragma unroll
    for (int j = 0; j < 4; ++j)
      Sd[(size_t)(h * TDC + iq0 + ty * 4 + i) * TDC + jk0 + tx * 4 + j] =
          acc[i][j] * 0.125f;
}

// ---------------------------------------------------------------------------
// FUSED: blk<1024 -> 26th-largest of 4 Sd rows; blk==1024 -> xmean2.
// ---------------------------------------------------------------------------
__global__ __launch_bounds__(256) void fused_kth_xm(
    const float* __restrict__ Sd, float* __restrict__ kth,
    const float* __restrict__ xp, float* __restrict__ xm) {
  int blk = blockIdx.x, tid = threadIdx.x;
  if (blk < 1024) {
    int lane = tid & 63;
    int b = blk * 4 + (tid >> 6);
    const float* row = &Sd[(size_t)b * TDC];
    float v[4];
#pragma unroll
    for (int j = 0; j < 4; ++j) v[j] = row[lane + 64 * j];
    float ans = 0.f;
    for (int it = 0; it < KSEL; ++it) {
      float lm = fmaxf(fmaxf(v[0], v[1]), fmaxf(v[2], v[3]));
#pragma unroll
      for (int off = 1; off < 64; off <<= 1) lm = fmaxf(lm, __shfl_xor(lm, off));
      if (it == KSEL - 1) { ans = lm; break; }
      unsigned long long ball =
          __ballot(v[0] == lm || v[1] == lm || v[2] == lm || v[3] == lm);
      int first = __ffsll(ball) - 1;
      if (lane == first) {
        if (v[0] == lm) v[0] = -INFINITY;
        else if (v[1] == lm) v[1] = -INFINITY;
        else if (v[2] == lm) v[2] = -INFINITY;
        else v[3] = -INFINITY;
      }
    }
    if (lane == 0) kth[b] = ans;
  } else {
    float4 s = {0.f, 0.f, 0.f, 0.f};
    for (int i = 0; i < 64; ++i) {
      float4 v = *(const float4*)&xp[i * Dm + tid * 4];
      s.x += v.x; s.y += v.y; s.z += v.z; s.w += v.w;
    }
    float4 o = {s.x * (1.f / 2048.f), s.y * (1.f / 2048.f),
                s.z * (1.f / 2048.f), s.w * (1.f / 2048.f)};
    *(float4*)&xm[tid * 4] = o;
  }
}

// ---------------------------------------------------------------------------
// FUSED: pidx<1280 -> split-j flash attention partial (swapped QK^T,
// gload_lds staging, defer-rescale, SHARED pen_s LDS — bit-identical values);
// pidx>=1280 -> vm (Vmean = xm @ wv^T).
// ---------------------------------------------------------------------------
__global__ __launch_bounds__(256) void fused_attn_vm(
    const ushort* __restrict__ Qh, const ushort* __restrict__ Ql,
    const ushort* __restrict__ Kh, const ushort* __restrict__ Kl,
    const ushort* __restrict__ Vth, const float* __restrict__ U,
    const float* __restrict__ Sd, const float* __restrict__ kth,
    const float* __restrict__ xm, const float* __restrict__ wv,
    float* __restrict__ Vm,
    ushort* __restrict__ Pacc, float* __restrict__ Pm, float* __restrict__ Pl) {
  int pidx = blockIdx.x;
  int tid = threadIdx.x;
  if (pidx >= 1280) {   // vm blocks
    int h = pidx - 1280;
    int r = h * 64 + (tid >> 2), q = tid & 3;
    const float* wrow = wv + (size_t)r * Dm + q * 256;
    const float* a = xm + q * 256;
    float s = 0.f;
    for (int k = 0; k < 256; k += 4) {
      float4 w4 = *(const float4*)&wrow[k];
      float4 a4 = *(const float4*)&a[k];
      s += w4.x * a4.x + w4.y * a4.y + w4.z * a4.z + w4.w * a4.w;
    }
    s += __shfl_xor(s, 1); s += __shfl_xor(s, 2);
    if (q == 0) Vm[r] = s;
    return;
  }
  int xcd = pidx & 7, idx = pidx >> 3;
  int h = xcd * 2 + (idx & 1);
  int p = idx >> 1;                       // 0..79 active (c,qt) pairs
  int c, qt;
  if (p < 32)      { c = 0; qt = p; }
  else if (p < 56) { c = 1; qt = p - 24; }
  else if (p < 72) { c = 2; qt = p - 40; }
  else             { c = 3; qt = p - 48; }
  int w = tid >> 6, l = tid & 63, l15 = l & 15, lg = l >> 4;
  int lrow = l >> 3, lc8 = l & 7;        // staging roles
  int i0 = qt * 64;
  int irow = i0 + 16 * w + l15;          // this lane's q-row
  int rloc = 16 * w + l15;               // row within tile

  __shared__ ushort KhS[64][64], KlS[64][64], VhS[64][64];
  __shared__ ushort Ps[4][16][72];
  __shared__ float pen_s[64][9];          // pad 9 -> conflict-free reads

  // pen-producer role: this thread computes pens for (prow, pjb..pjb+1)
  int prow = tid >> 2;                    // 0..63
  int pjb  = (tid & 3) * 2;               // 0,2,4,6
  float puu; { float t = U[i0 + prow]; puu = 1.f + fminf(fmaxf(t, 0.f), 1.f); }
  int pi8 = (i0 + prow) >> 3;
  float pkvu = kth[h * TDC + pi8] * puu;  // fl(kv*u), matches reference
  const float* pSdRow = Sd + ((size_t)h * TDC + pi8) * TDC;

  size_t qoff = ((size_t)h * Tq + irow) * HDC;
  bf16x8 qh0 = *(const bf16x8*)(Qh + qoff + lg * 8);
  bf16x8 qh1 = *(const bf16x8*)(Qh + qoff + 32 + lg * 8);
  bf16x8 ql0 = *(const bf16x8*)(Ql + qoff + lg * 8);
  bf16x8 ql1 = *(const bf16x8*)(Ql + qoff + 32 + lg * 8);

  float mrow = -INFINITY, lrow_acc = 0.f;
  f32x4 acc[4] = {};

  int jt1 = min(c * CH + CH, qt + 1);
  for (int jt = c * CH; jt < jt1; ++jt) {
    int j0 = jt * 64;
    __syncthreads();
    // async stage K hi/lo + V
#pragma unroll
    for (int hh = 0; hh < 2; ++hh) {
      int row = 16 * w + hh * 8 + lrow;
      int scol = (lc8 ^ (row & 7)) * 8;
      size_t ko = ((size_t)h * Tq + j0 + row) * HDC + scol;
      size_t vo = ((size_t)h * HDC + row) * Tq + j0 + scol;
      gload16(&Kh[ko], &KhS[16 * w + hh * 8][0]);
      gload16(&Kl[ko], &KlS[16 * w + hh * 8][0]);
      gload16(&Vth[vo], &VhS[16 * w + hh * 8][0]);
    }

    // shared pen production (exact fp32 reference op order) — overlaps loads
    {
      int jbase = j0 >> 3;
#pragma unroll
      for (int q = 0; q < 2; ++q) {
        float sdv = pSdRow[jbase + pjb + q];
        float arg = (sdv * puu - pkvu) * 10.f;
        float mk;
        if (arg >= 0.f) mk = 1.f / (1.f + expf(-arg));
        else { float e = expf(arg); mk = e / (1.f + e); }
        pen_s[prow][pjb + q] = (1.f - mk) * (-1.0e9f);
      }
    }
    __syncthreads();   // drains vmcnt -> staged K/V + pen_s visible

    // S^T = K Q^T (split: 24 MFMA). Lane holds S[irow][j0+nt*16+lg*4+rg].
    f32x4 s[4] = {};
#pragma unroll
    for (int nt = 0; nt < 4; ++nt) {
      int kr = nt * 16 + l15;
      int s0 = ((0 + lg) ^ (kr & 7)) * 8;
      int s1 = ((4 + lg) ^ (kr & 7)) * 8;
      bf16x8 ah0 = *(const bf16x8*)&KhS[kr][s0];
      bf16x8 ah1 = *(const bf16x8*)&KhS[kr][s1];
      bf16x8 al0 = *(const bf16x8*)&KlS[kr][s0];
      bf16x8 al1 = *(const bf16x8*)&KlS[kr][s1];
      s[nt] = __builtin_amdgcn_mfma_f32_16x16x32_bf16(ah0, qh0, s[nt], 0, 0, 0);
      s[nt] = __builtin_amdgcn_mfma_f32_16x16x32_bf16(ah1, qh1, s[nt], 0, 0, 0);
      s[nt] = __builtin_amdgcn_mfma_f32_16x16x32_bf16(al0, qh0, s[nt], 0, 0, 0);
      s[nt] = __builtin_amdgcn_mfma_f32_16x16x32_bf16(al1, qh1, s[nt], 0, 0, 0);
      s[nt] = __builtin_amdgcn_mfma_f32_16x16x32_bf16(ah0, ql0, s[nt], 0, 0, 0);
      s[nt] = __builtin_amdgcn_mfma_f32_16x16x32_bf16(ah1, ql1, s[nt], 0, 0, 0);
    }

    // pens from LDS (values identical to per-lane computation)
    float pen[4];
#pragma unroll
    for (int nt = 0; nt < 4; ++nt) pen[nt] = pen_s[rloc][nt * 2 + (lg >> 1)];

    // logits + in-lane online softmax for row irow
    bool diag = (jt == qt);
    float lgv[4][4];
    float tmax = -INFINITY;
    if (diag) {
#pragma unroll
      for (int nt = 0; nt < 4; ++nt)
#pragma unroll
        for (int rg = 0; rg < 4; ++rg) {
          int jj = j0 + nt * 16 + lg * 4 + rg;
          float lv = s[nt][rg] * 0.125f + ((jj > irow) ? -1.0e9f : pen[nt]);
          lgv[nt][rg] = lv;
          tmax = fmaxf(tmax, lv);
        }
    } else {
#pragma unroll
      for (int nt = 0; nt < 4; ++nt)
#pragma unroll
        for (int rg = 0; rg < 4; ++rg) {
          float lv = s[nt][rg] * 0.125f + pen[nt];
          lgv[nt][rg] = lv;
          tmax = fmaxf(tmax, lv);
        }
    }
    tmax = fmaxf(tmax, __shfl_xor(tmax, 16));
    tmax = fmaxf(tmax, __shfl_xor(tmax, 32));
    float mnew = fmaxf(mrow, tmax);
    float ps = 0.f;
#pragma unroll
    for (int nt = 0; nt < 4; ++nt) {
      float p0 = __expf(lgv[nt][0] - mnew);
      float p1 = __expf(lgv[nt][1] - mnew);
      float p2 = __expf(lgv[nt][2] - mnew);
      float p3 = __expf(lgv[nt][3] - mnew);
      ps += (p0 + p1) + (p2 + p3);        // fp32 denominator
      uint2 pk;
      asm("v_cvt_pk_bf16_f32 %0, %1, %2" : "=v"(pk.x) : "v"(p0), "v"(p1));
      asm("v_cvt_pk_bf16_f32 %0, %1, %2" : "=v"(pk.y) : "v"(p2), "v"(p3));
      *(uint2*)&Ps[w][l15][nt * 16 + lg * 4] = pk;
    }
    ps += __shfl_xor(ps, 16);
    ps += __shfl_xor(ps, 32);
    // defer-rescale: when no lane's max advanced, sc==1.0 exactly ->
    // skipping the rescale is bit-identical.
    if (!__all(tmax <= mrow)) {
      float sc = __expf(mrow - mnew);     // exp(-inf)=0 on first tile
      lrow_acc = lrow_acc * sc + ps;
      mrow = mnew;
      float scr[4];
#pragma unroll
      for (int rg = 0; rg < 4; ++rg) scr[rg] = __shfl(sc, lg * 4 + rg);
#pragma unroll
      for (int ntd = 0; ntd < 4; ++ntd)
#pragma unroll
        for (int rg = 0; rg < 4; ++rg) acc[ntd][rg] *= scr[rg];
    } else {
      lrow_acc += ps;
    }

    // O += P V  (hi-only V: 8 MFMA)
#pragma unroll
    for (int kst = 0; kst < 2; ++kst) {
      bf16x8 pa = *(const bf16x8*)&Ps[w][l15][kst * 32 + lg * 8];
#pragma unroll
      for (int ntd = 0; ntd < 4; ++ntd) {
        int vr = ntd * 16 + l15;
        int sv = ((kst * 4 + lg) ^ (vr & 7)) * 8;
        bf16x8 vbh = *(const bf16x8*)&VhS[vr][sv];
        acc[ntd] = __builtin_amdgcn_mfma_f32_16x16x32_bf16(pa, vbh, acc[ntd], 0, 0, 0);
      }
    }
  }

  size_t rowbase = ((size_t)c * NHC + h) * Tq + i0 + 16 * w;
  if (lg == 0) {
    Pm[rowbase + l15] = mrow;
    Pl[rowbase + l15] = lrow_acc;
  }
#pragma unroll
  for (int ntd = 0; ntd < 4; ++ntd)
#pragma unroll
    for (int rg = 0; rg < 4; ++rg)
      Pacc[(rowbase + lg * 4 + rg) * HDC + ntd * 16 + l15] = f2bf(acc[ntd][rg]);
}

// ---------------------------------------------------------------------------
// Merge split-j partials -> AO split bf16 hi/lo [t][1024]  (untouched)
// ---------------------------------------------------------------------------
__global__ __launch_bounds__(256) void attn_merge(
    const ushort* __restrict__ Pacc, const float* __restrict__ Pm,
    const float* __restrict__ Pl, const float* __restrict__ Vm,
    ushort* __restrict__ AOh, ushort* __restrict__ AOl) {
  int qt = blockIdx.x, h = blockIdx.y;
  int tid = threadIdx.x;
  int r = tid >> 2, q4 = tid & 3;
  int gi = qt * 64 + r;
  int nc = (qt >> 3) + 1;
  float M = -INFINITY, mv[4];
#pragma unroll
  for (int cc = 0; cc < 4; ++cc) {
    mv[cc] = (cc < nc) ? Pm[((size_t)cc * NHC + h) * Tq + gi] : -INFINITY;
    M = fmaxf(M, mv[cc]);
  }
  if (M == -1.0e9f) {   // all-masked: reference softmax uniform over ALL rows
#pragma unroll
    for (int dd = 0; dd < 16; dd += 4) {
      int d = q4 * 16 + dd;
      float4 v = *(const float4*)&Vm[h * HDC + d];
      float vv[4] = {v.x, v.y, v.z, v.w};
      ushort4 uh, ul;
      ushort* uhp = &uh.x; ushort* ulp = &ul.x;
#pragma unroll
      for (int j = 0; j < 4; ++j) {
        ushort hh = f2bf(vv[j]);
        uhp[j] = hh; ulp[j] = f2bf(vv[j] - bf2f(hh));
      }
      *(ushort4*)&AOh[(size_t)gi * Dm + h * HDC + d] = uh;
      *(ushort4*)&AOl[(size_t)gi * Dm + h * HDC + d] = ul;
    }
    return;
  }
  float W[4], L = 0.f;
#pragma unroll
  for (int cc = 0; cc < 4; ++cc) {
    W[cc] = (cc < nc) ? __expf(mv[cc] - M) : 0.f;
    if (cc < nc) L += Pl[((size_t)cc * NHC + h) * Tq + gi] * W[cc];
  }
  float invL = 1.f / L;
#pragma unroll
  for (int dd = 0; dd < 16; dd += 4) {
    int d = q4 * 16 + dd;
    float o[4] = {0.f, 0.f, 0.f, 0.f};
    for (int cc = 0; cc < nc; ++cc) {
      bf16x4 a = *(const bf16x4*)&Pacc[(((size_t)cc * NHC + h) * Tq + gi) * HDC + d];
#pragma unroll
      for (int j = 0; j < 4; ++j) o[j] += bf2f((ushort)a[j]) * W[cc];
    }
    ushort4 uh, ul;
    ushort* uhp = &uh.x; ushort* ulp = &ul.x;
#pragma unroll
    for (int j = 0; j < 4; ++j) {
      float vv = o[j] * invL;
      ushort hh = f2bf(vv);
      uhp[j] = hh; ulp[j] = f2bf(vv - bf2f(hh));
    }
    *(ushort4*)&AOh[(size_t)gi * Dm + h * HDC + d] = uh;
    *(ushort4*)&AOl[(size_t)gi * Dm + h * HDC + d] = ul;
  }
}

// ---------------------------------------------------------------------------
extern "C" void kernel_launch(void* const* d_in, const int* in_sizes, int n_in,
                              void* d_out, int out_size, void* d_ws, size_t ws_size,
                              hipStream_t stream) {
  const float* x  = (const float*)d_in[0];
  const float* U  = (const float*)d_in[1];
  const float* wq = (const float*)d_in[2];
  const float* wk = (const float*)d_in[3];
  const float* wv = (const float*)d_in[4];
  const float* wo = (const float*)d_in[5];
  float* out = (float*)d_out;

  float* fw = (float*)d_ws;
  const size_t TD_ = (size_t)Tq * Dm;          // 2M elements
  const size_t WW_ = (size_t)Dm * Dm;          // 1M elements
  const size_t QD_ = (size_t)TDC * Dm;         // 256K elements
  float* Qd  = fw;                 fw += QD_;
  float* Kd  = fw;                 fw += QD_;
  float* Sd  = fw;                 fw += (size_t)NHC * TDC * TDC;
  float* kth = fw;                 fw += 4096;
  float* Vm  = fw;                 fw += 4096;
  float* xm  = fw;                 fw += 4096;
  float* xp  = fw;                 fw += 64 * Dm;
  float* Pm  = fw;                 fw += 4 * NHC * Tq;
  float* Pl  = fw;                 fw += 4 * NHC * Tq;
  ushort* uw = (ushort*)fw;
  ushort* xh   = uw;               uw += TD_;
  ushort* xl   = uw;               uw += TD_;
  ushort* wqh  = uw;               uw += WW_;
  ushort* wql  = uw;               uw += WW_;
  ushort* wkh  = uw;               uw += WW_;
  ushort* wkl  = uw;               uw += WW_;
  ushort* wvh  = uw;               uw += WW_;
  ushort* wvl  = uw;               uw += WW_;
  ushort* woh  = uw;               uw += WW_;
  ushort* wol  = uw;               uw += WW_;
  ushort* Qh   = uw;               uw += TD_;
  ushort* Ql   = uw;               uw += TD_;
  ushort* Kh   = uw;               uw += TD_;
  ushort* Kl   = uw;               uw += TD_;
  ushort* Vth  = uw;               uw += TD_;
  ushort* Pacc = uw;               uw += (size_t)4 * NHC * Tq * HDC;
  // AO aliases x's split buffers (lifetimes disjoint)
  ushort* AOh = xh;
  ushort* AOl = xl;

  dim3 bb(256);
  // 1) fused splits (flat grid)
  cast_split_all<<<dim3(6144), bb, 0, stream>>>(
      x, wq, wk, wv, wo, xh, xl, wqh, wql, wkh, wkl, wvh, wvl, woh, wol);
  // 2) ALL projection GEMMs, exactly 512 blocks (qkd+xpart first, qkv swizzled)
  fused_gemms<<<dim3(512), bb, 0, stream>>>(
      x, wq, wk, Qd, Kd, xp,
      xh, xl, wqh, wql, wkh, wkl, wvh, wvl, Qh, Ql, Kh, Kl, Vth);
  // 3) mask scores (exact fp32)
  sd_kernel<<<dim3(4, 4, NHC), bb, 0, stream>>>(Qd, Kd, Sd);
  // 4) fused: kth selection + xmean2
  fused_kth_xm<<<dim3(1025), bb, 0, stream>>>(Sd, kth, xp, xm);
  // 5) fused: split-j flash attention (shared pen_s) + vm
  fused_attn_vm<<<dim3(1296), bb, 0, stream>>>(
      Qh, Ql, Kh, Kl, Vth, U, Sd, kth, xm, wv, Vm, Pacc, Pm, Pl);
  // 6) merge partials
  attn_merge<<<dim3(Tq / 64, NHC), bb, 0, stream>>>(Pacc, Pm, Pl, Vm, AOh, AOl);
  // 7) output projection (128x64, 256 blocks -> 1/CU)
  gemm_out<<<dim3(16, 16), dim3(512), 0, stream>>>(AOh, AOl, woh, wol, out);
}